// Round 18
// baseline (328.593 us; speedup 1.0000x reference)
//
#include <hip/hip_runtime.h>

#define NB 64
#define T 320
#define D 768
#define WD 32
#define NSTEP 639
#define NBLK 80
#define BSTRIDE (NBLK * 1024)
#define BIG 1e30f
#define LOG2E 1.44269504088896340736f

// DPP lane rotations (VALU, no LDS pipe): ror1 = lane l <- lane (l-1)&63,
// rol1 = lane l <- lane (l+1)&63. gfx9-lineage wave_ror:1/wave_rol:1.
__device__ __forceinline__ float dpp_ror1(float v) {
  return __int_as_float(__builtin_amdgcn_update_dpp(
      0, __float_as_int(v), 0x13C, 0xF, 0xF, true));
}
__device__ __forceinline__ float dpp_rol1(float v) {
  return __int_as_float(__builtin_amdgcn_update_dpp(
      0, __float_as_int(v), 0x134, 0xF, 0xF, true));
}

// ---------------- K_prep: WeT[c][k] = W[k][c]*wscale[k];  beff[k] ----------------
__global__ __launch_bounds__(256) void prep_kernel(
    const float* __restrict__ W, const float* __restrict__ bias,
    const float* __restrict__ wscale, const float* __restrict__ wshift,
    float* __restrict__ WeT, float* __restrict__ beff) {
  int i = blockIdx.x * 256 + threadIdx.x;  // i = c*32 + k
  int c = i >> 5, k = i & 31;
  WeT[i] = W[k * D + c] * wscale[k];
  if (i < WD) beff[i] = bias[i] * wscale[i] + wshift[i];
}

// ---------------- K1: projection v5 (unchanged) ----------------
__global__ __launch_bounds__(256) void proj_kernel(
    const float* __restrict__ x, const float* __restrict__ y,
    const float* __restrict__ WeT, const float* __restrict__ beff,
    float* __restrict__ xw, float* __restrict__ yw) {
  __shared__ float lds[8448];  // = max(64*129, 4*64*33) floats = 33.8 KB
  int tid = threadIdx.x;
  int w = tid >> 6, l = tid & 63;
  int rbase = blockIdx.x * 64;
  float acc[32];
#pragma unroll
  for (int k = 0; k < 32; ++k) acc[k] = 0.f;
#pragma clang loop unroll(disable)
  for (int ch = 0; ch < 6; ++ch) {
    __syncthreads();  // Xl region safe to overwrite
#pragma unroll
    for (int p = 0; p < 8; ++p) {
      int idx = p * 256 + tid;  // 0..2047
      int row = idx >> 5;       // 0..63
      int c4 = idx & 31;        // 0..31
      int r = rbase + row;
      const float* src = (r < NB * T) ? x + (size_t)r * D
                                      : y + (size_t)(r - NB * T) * D;
      float4 v = *(const float4*)(src + ch * 128 + c4 * 4);
      lds[row * 129 + c4 * 4 + 0] = v.x;
      lds[row * 129 + c4 * 4 + 1] = v.y;
      lds[row * 129 + c4 * 4 + 2] = v.z;
      lds[row * 129 + c4 * 4 + 3] = v.w;
    }
    __syncthreads();
    int woff = __builtin_amdgcn_readfirstlane((ch * 128 + w * 32) * 32);
    const float* wp = WeT + woff;
#pragma unroll
    for (int cc = 0; cc < 32; ++cc) {
      float xv = lds[l * 129 + w * 32 + cc];
#pragma unroll
      for (int k = 0; k < 32; ++k)
        acc[k] = fmaf(wp[cc * 32 + k], xv, acc[k]);
    }
  }
  __syncthreads();  // all Xl reads done; reuse lds as part[4][64][33]
#pragma unroll
  for (int k = 0; k < 32; ++k) lds[w * 2112 + l * 33 + k] = acc[k];
  __syncthreads();
  int idx = tid * 8;
  int row = idx >> 5;  // 0..63
  int k0 = idx & 31;   // 0,8,16,24
  float o[8];
#pragma unroll
  for (int e = 0; e < 8; ++e)
    o[e] = lds[0 * 2112 + row * 33 + k0 + e] + lds[1 * 2112 + row * 33 + k0 + e] +
           lds[2 * 2112 + row * 33 + k0 + e] + lds[3 * 2112 + row * 33 + k0 + e] +
           beff[k0 + e];
  int rr = rbase + row;
  float* dst = (rr < NB * T) ? xw + (size_t)rr * WD + k0
                             : yw + (size_t)(rr - NB * T) * WD + k0;
  float4 o0 = {o[0], o[1], o[2], o[3]}, o1 = {o[4], o[5], o[6], o[7]};
  *(float4*)dst = o0;
  *(float4*)(dst + 4) = o1;
}

// ---------------- K0: tiled banded dist, LDS-staged rows (unchanged) ----------------
__global__ __launch_bounds__(256) void dist_kernel(
    const float* __restrict__ xw, const float* __restrict__ yw,
    float* __restrict__ dc) {
  __shared__ float xs[64][33];
  __shared__ float ys[64][33];
  int b = blockIdx.y;
  int cidx = blockIdx.x;            // 0..19
  int t1c = (cidx >> 2) * 64;       // 0,64,...,256
  int t2c = t1c - 88 + (cidx & 3) * 64;  // may be negative / >T
  int tid = threadIdx.x;
  {
    int r = tid >> 2, c4 = tid & 3;
    const float* sx = xw + ((size_t)b * T + t1c + r) * WD;
    *(float4*)&xs[r][c4 * 4] = *(const float4*)(sx + c4 * 4);
    *(float4*)&xs[r][(c4 + 4) * 4] = *(const float4*)(sx + (c4 + 4) * 4);
    int t2r = t2c + r;
    if ((unsigned)t2r < (unsigned)T) {
      const float* sy = yw + ((size_t)b * T + t2r) * WD;
      *(float4*)&ys[r][c4 * 4] = *(const float4*)(sy + c4 * 4);
      *(float4*)&ys[r][(c4 + 4) * 4] = *(const float4*)(sy + (c4 + 4) * 4);
    }
  }
  __syncthreads();
  int ts1 = (tid >> 4) * 4;  // 0..60
  int ts2 = (tid & 15) * 4;  // 0..60
  float acc[4][4];
#pragma unroll
  for (int i = 0; i < 4; ++i)
#pragma unroll
    for (int j = 0; j < 4; ++j) acc[i][j] = 0.f;
#pragma unroll
  for (int c4 = 0; c4 < 8; ++c4) {
    float4 xv[4], yv[4];
#pragma unroll
    for (int i = 0; i < 4; ++i) xv[i] = *(const float4*)&xs[ts1 + i][c4 * 4];
#pragma unroll
    for (int j = 0; j < 4; ++j) yv[j] = *(const float4*)&ys[ts2 + j][c4 * 4];
#pragma unroll
    for (int i = 0; i < 4; ++i)
#pragma unroll
      for (int j = 0; j < 4; ++j) {
        float d0 = xv[i].x - yv[j].x, d1 = xv[i].y - yv[j].y;
        float d2 = xv[i].z - yv[j].z, d3 = xv[i].w - yv[j].w;
        float s = acc[i][j];
        s = fmaf(d0, d0, s); s = fmaf(d1, d1, s);
        s = fmaf(d2, d2, s); s = fmaf(d3, d3, s);
        acc[i][j] = s;
      }
  }
  float* dcb = dc + (size_t)b * BSTRIDE;
#pragma unroll
  for (int i = 0; i < 4; ++i) {
#pragma unroll
    for (int j = 0; j < 4; ++j) {
      int t1 = t1c + ts1 + i;
      int t2 = t2c + ts2 + j;
      int dt = t2 - t1;
      if ((unsigned)t2 < (unsigned)T && dt >= -81 && dt <= 80) {
        int d = t1 + t2;
        int par = (d + 1) & 1;
        int base = (d + 81 - par) >> 1;
        int a = base - t1;
        dcb[((d >> 3) << 10) + (a << 3) + (d & 7)] = acc[i][j] * LOG2E;
      }
    }
  }
}

// ---------------- K2: single-wave banded DP, DPP exchange, base-2 softmin (unchanged) ----------------
#define FSTEP(DP_, DS_, PAR, DVAL)                                             \
  {                                                                            \
    const int d_ = (DVAL);                                                     \
    const int base_ = (d_ + 81 - (PAR)) >> 1;                                  \
    float shP, shS;                                                            \
    if (PAR) { shP = dpp_rol1((l == 0) ? v0b : v0); shS = dpp_rol1(v0b); }     \
    else     { shP = dpp_ror1(v1); shS = dpp_ror1((l == 63) ? v1 : v1b); }     \
    int t1 = base_ - l, t2 = d_ - t1;                                          \
    {                                                                          \
      bool valid = ((unsigned)t1 < (unsigned)T) && ((unsigned)t2 < (unsigned)T); \
      float up, left, diag;                                                    \
      if (PAR) { left = v0; up = shP; diag = v1; }                             \
      else     { up = v1; left = (l == 0) ? 0.f : shP; diag = v0; }            \
      float cu = (t1 > 0) ? up : BIG;                                          \
      float cl = (t2 > 0) ? left : BIG;                                        \
      float cd = (t1 > 0 && t2 > 0) ? diag : BIG;                              \
      float mn = fminf(fminf(cu, cl), cd);                                     \
      float mx = fmaxf(fmaxf(cu, cl), cd);                                     \
      float md = fmaxf(fminf(cu, cl), fminf(fmaxf(cu, cl), cd));               \
      float ss = 1.f + __builtin_amdgcn_exp2f(mn - md) +                       \
                 __builtin_amdgcn_exp2f(mn - mx);                              \
      float val = (DP_) + mn - __builtin_amdgcn_logf(ss);                      \
      if ((DVAL) == 0) val = (DP_);                                            \
      if (valid) {                                                             \
        if (PAR) v1 = val; else v0 = val;                                      \
        outb[t1 * T + t2] = val;                                               \
      }                                                                        \
    }                                                                          \
    {                                                                          \
      int t1b = t1 - 64, t2b = t2 + 64;                                        \
      bool valid = (l < 17) && ((unsigned)t1b < (unsigned)T) &&                \
                   ((unsigned)t2b < (unsigned)T);                              \
      float up, left, diag;                                                    \
      if (PAR) { left = v0b; up = (l == 16) ? 0.f : shS; diag = v1b; }         \
      else     { up = v1b; left = shS; diag = v0b; }                           \
      float cu = (t1b > 0) ? up : BIG;                                         \
      float cl = (t2b > 0) ? left : BIG;                                       \
      float cd = (t1b > 0 && t2b > 0) ? diag : BIG;                            \
      float mn = fminf(fminf(cu, cl), cd);                                     \
      float mx = fmaxf(fmaxf(cu, cl), cd);                                     \
      float md = fmaxf(fminf(cu, cl), fminf(fmaxf(cu, cl), cd));               \
      float ss = 1.f + __builtin_amdgcn_exp2f(mn - md) +                       \
                 __builtin_amdgcn_exp2f(mn - mx);                              \
      float val = (DS_) + mn - __builtin_amdgcn_logf(ss);                      \
      if (valid) {                                                             \
        if (PAR) v1b = val; else v0b = val;                                    \
        outb[t1b * T + t2b] = val;                                             \
      }                                                                        \
    }                                                                          \
  }

#define SSTEP(DP_, DS_, PAR, IOFF)                                             \
  {                                                                            \
    float shP, shS;                                                            \
    if (PAR) { shP = dpp_rol1((l == 0) ? v0b : v0); shS = dpp_rol1(v0b); }     \
    else     { shP = dpp_ror1(v1); shS = dpp_ror1((l == 63) ? v1 : v1b); }     \
    {                                                                          \
      float up, left, diag;                                                    \
      if (PAR) { left = v0; up = shP; diag = v1; }                             \
      else     { up = v1; left = (l == 0) ? 0.f : shP; diag = v0; }            \
      float mn = fminf(fminf(up, left), diag);                                 \
      float mx = fmaxf(fmaxf(up, left), diag);                                 \
      float md = fmaxf(fminf(up, left), fminf(fmaxf(up, left), diag));         \
      float ss = 1.f + __builtin_amdgcn_exp2f(mn - md) +                       \
                 __builtin_amdgcn_exp2f(mn - mx);                              \
      float val = (DP_) + mn - __builtin_amdgcn_logf(ss);                      \
      if (PAR) v1 = val; else v0 = val;                                        \
      outb[io + (IOFF)] = val;                                                 \
    }                                                                          \
    {                                                                          \
      float up, left, diag;                                                    \
      if (PAR) { left = v0b; up = (l == 16) ? 0.f : shS; diag = v1b; }         \
      else     { up = v1b; left = shS; diag = v0b; }                           \
      float mn = fminf(fminf(up, left), diag);                                 \
      float mx = fmaxf(fmaxf(up, left), diag);                                 \
      float md = fmaxf(fminf(up, left), fminf(fmaxf(up, left), diag));         \
      float ss = 1.f + __builtin_amdgcn_exp2f(mn - md) +                       \
                 __builtin_amdgcn_exp2f(mn - mx);                              \
      float val = (DS_) + mn - __builtin_amdgcn_logf(ss);                      \
      if (PAR) v1b = val; else v0b = val;                                      \
      if (l < 17) outb[ioS + (IOFF)] = val;                                    \
    }                                                                          \
  }

#define LOADBLK(R0, R1, S0v, S1v, DBLK)                                        \
  {                                                                            \
    const float4* q_ = (const float4*)(dcb + (DBLK) * 1024 + l * 8);           \
    R0 = q_[0]; R1 = q_[1];                                                    \
    const float4* q2_ = (const float4*)(dcb + (DBLK) * 1024 + (64 + l) * 8);   \
    S0v = q2_[0]; S1v = q2_[1];                                                \
  }

#define BLK8_F(P0, P1, S0v, S1v, DB)                                           \
  FSTEP(P0.x, S0v.x, 1, (DB) + 0) FSTEP(P0.y, S0v.y, 0, (DB) + 1)              \
  FSTEP(P0.z, S0v.z, 1, (DB) + 2) FSTEP(P0.w, S0v.w, 0, (DB) + 3)              \
  FSTEP(P1.x, S1v.x, 1, (DB) + 4) FSTEP(P1.y, S1v.y, 0, (DB) + 5)              \
  FSTEP(P1.z, S1v.z, 1, (DB) + 6) FSTEP(P1.w, S1v.w, 0, (DB) + 7)

#define BLK8_S(P0, P1, S0v, S1v)                                               \
  SSTEP(P0.x, S0v.x, 1, 0)   SSTEP(P0.y, S0v.y, 0, 320)                        \
  SSTEP(P0.z, S0v.z, 1, 321) SSTEP(P0.w, S0v.w, 0, 641)                        \
  io += 642; ioS += 642;                                                       \
  SSTEP(P1.x, S1v.x, 1, 0)   SSTEP(P1.y, S1v.y, 0, 320)                        \
  SSTEP(P1.z, S1v.z, 1, 321) SSTEP(P1.w, S1v.w, 0, 641)                        \
  io += 642; ioS += 642;

__global__ __launch_bounds__(64) void dtw_kernel(
    const float* __restrict__ dc, float* __restrict__ path) {
  int b = blockIdx.x;
  int l = threadIdx.x;
  const float* dcb = dc + (size_t)b * BSTRIDE;
  float* outb = path + (size_t)b * T * T;
  float v0 = 0.f, v1 = 0.f, v0b = 0.f, v1b = 0.f;
  float4 aP0, aP1, aS0, aS1, bP0, bP1, bS0, bS1;
  int io = 0, ioS = 0;

  // d = 0: cell (0,0) = slot 81 = pair a=40 par1. Layout index: a*8+k = 320.
  if (l == 40) {
    float d00 = dcb[320];
    v1 = d00;
    outb[0] = d00;
  }
  LOADBLK(aP0, aP1, aS0, aS1, 0)
#pragma clang loop unroll(disable)
  for (int it = 0; it < 6; ++it) {
    int dbase = it * 16;
    int blk = it * 2;
    LOADBLK(bP0, bP1, bS0, bS1, blk + 1)
    BLK8_F(aP0, aP1, aS0, aS1, dbase)
    LOADBLK(aP0, aP1, aS0, aS1, blk + 2)
    BLK8_F(bP0, bP1, bS0, bS1, dbase + 8)
  }
  io = 28168 - 319 * l;
  ioS = io - 20416;
#pragma clang loop unroll(disable)
  for (int it = 0; it < 27; ++it) {
    int blk = 12 + it * 2;
    LOADBLK(bP0, bP1, bS0, bS1, blk + 1)
    BLK8_S(aP0, aP1, aS0, aS1)
    LOADBLK(aP0, aP1, aS0, aS1, blk + 2)
    BLK8_S(bP0, bP1, bS0, bS1)
  }
#pragma clang loop unroll(disable)
  for (int it = 0; it < 6; ++it) {
    int dbase = 528 + it * 16;
    int blk = 66 + it * 2;
    LOADBLK(bP0, bP1, bS0, bS1, blk + 1)
    BLK8_F(aP0, aP1, aS0, aS1, dbase)
    LOADBLK(aP0, aP1, aS0, aS1, blk + 2)
    BLK8_F(bP0, bP1, bS0, bS1, dbase + 8)
  }
  LOADBLK(bP0, bP1, bS0, bS1, 79)
  BLK8_F(aP0, aP1, aS0, aS1, 624)
  FSTEP(bP0.x, bS0.x, 1, 632) FSTEP(bP0.y, bS0.y, 0, 633)
  FSTEP(bP0.z, bS0.z, 1, 634) FSTEP(bP0.w, bS0.w, 0, 635)
  FSTEP(bP1.x, bS1.x, 1, 636) FSTEP(bP1.y, bS1.y, 0, 637)
  FSTEP(bP1.z, bS1.z, 1, 638)
}

// ---------------- K3: row softmax; path holds base-2 values -> exp2 ----------------
__global__ __launch_bounds__(T) void softmax_kernel(float* __restrict__ path,
                                                    float* __restrict__ cvec) {
  __shared__ float sm1[5], sm2[5];
  int row = blockIdx.x;
  int t1 = row % T;
  int j = threadIdx.x;
  float* p = path + (size_t)row * T;
  bool in = (j >= t1 - 81) && (j <= t1 + 80);
  float v = in ? p[j] : 0.f;  // out-of-band cells are exact 0 in the reference
  float m = v;
#pragma unroll
  for (int off = 32; off >= 1; off >>= 1) m = fminf(m, __shfl_xor(m, off, 64));
  int w = j >> 6;
  if ((j & 63) == 0) sm1[w] = m;
  __syncthreads();
  m = fminf(fminf(fminf(sm1[0], sm1[1]), fminf(sm1[2], sm1[3])), sm1[4]);
  // v, m are DP values scaled by log2e; exp2(m - v) == exp(m_nats - v_nats)
  float e = __builtin_amdgcn_exp2f(m - v);
  float s = e;
#pragma unroll
  for (int off = 32; off >= 1; off >>= 1) s += __shfl_xor(s, off, 64);
  if ((j & 63) == 0) sm2[w] = s;
  __syncthreads();
  s = sm2[0] + sm2[1] + sm2[2] + sm2[3] + sm2[4];
  p[j] = e / s;
  if (j == 0) cvec[row] = __builtin_amdgcn_exp2f(m - 0.f) / s;  // == out-of-band p[j]
}

// ---------------- K3g: g[b][d] = sum_t cvec[b,t] * x[b,t,d] ----------------
__global__ __launch_bounds__(256) void gk_kernel(
    const float* __restrict__ x, const float* __restrict__ cvec,
    float* __restrict__ g) {
  int b = blockIdx.y;
  int d0 = blockIdx.x * 256 + threadIdx.x;
  const float* xb = x + (size_t)b * T * D + d0;
  const float* cb = cvec + b * T;  // wave-uniform reads
  float s = 0.f;
  for (int t = 0; t < T; ++t) s = fmaf(cb[t], xb[(size_t)t * D], s);
  g[b * D + d0] = s;
}

// ---------------- K3b: column scale, band-window + Cb identity (unchanged) ----------------
__global__ __launch_bounds__(256) void colsum_kernel(
    const float* __restrict__ path, const float* __restrict__ cvec,
    float* __restrict__ scale) {
  __shared__ float red[4][64];
  __shared__ float cbred[4];
  int b = blockIdx.y;
  int tid = threadIdx.x;
  int l = tid & 63, tq = tid >> 6;
  int j = blockIdx.x * 64 + l;
  const float* cb = cvec + b * T;
  // Cb
  float c = cb[tid];
  if (tid < 64) c += cb[256 + tid];
#pragma unroll
  for (int off = 32; off >= 1; off >>= 1) c += __shfl_xor(c, off, 64);
  if (l == 0) cbred[tq] = c;
  // band-window quarter sum
  float s = 0.f;
  int t0 = j - 80 + tq * 41;
  const float* p = path + (size_t)b * T * T + j;
#pragma unroll 4
  for (int i = 0; i < 41; ++i) {
    int t = t0 + i;
    if ((unsigned)t < (unsigned)T) s += p[(size_t)t * T] - cb[t];
  }
  red[tq][l] = s;
  __syncthreads();
  if (tq == 0) {
    float cs = red[0][l] + red[1][l] + red[2][l] + red[3][l] +
               (cbred[0] + cbred[1] + cbred[2] + cbred[3]);
    scale[b * T + j] = 1.f / (cs + 1e-10f);
  }
}

// ---------------- K4: banded bmm, TKB=32 (half the barrier/drain events) ----------------
// Window aligned to 32: added rows are exact-zero P' contributions (out-of-band
// P == cvec bitwise), so accumulation is unchanged. All window lengths
// {160,224,256,224,160} divide by 32; T=320 ensures rows stay in range.
#define TSB 64
#define TDB 128
#define TKB 32
__global__ __launch_bounds__(256) void bmm_kernel(
    const float* __restrict__ path, const float* __restrict__ x,
    const float* __restrict__ cvec, const float* __restrict__ g,
    const float* __restrict__ scale, float* __restrict__ out) {
  __shared__ __align__(16) float Pl[TKB][TSB];   // 8 KB
  __shared__ __align__(16) float Xl[TKB][TDB];   // 16 KB
  int bid = blockIdx.x;
  int wgid = (bid & 7) * 240 + (bid >> 3);
  int b = wgid / 30;
  int r = wgid - b * 30;
  int s0 = (r / 6) * TSB;
  int d0 = (r % 6) * TDB;
  int tid = threadIdx.x;
  int ts = tid & 15, td = tid >> 4;  // 16 s-groups (4 rows) x 16 d-groups (8 cols)
  const float* pb = path + (size_t)b * T * T;
  const float* xb = x + (size_t)b * T * D;
  const float* cb = cvec + b * T;
  float acc[4][8];
  {
    const float* gb = g + b * D + d0 + td * 8;
    float4 g0 = *(const float4*)gb;
    float4 g1 = *(const float4*)(gb + 4);
    float gv[8] = {g0.x, g0.y, g0.z, g0.w, g1.x, g1.y, g1.z, g1.w};
#pragma unroll
    for (int i = 0; i < 4; ++i)
#pragma unroll
      for (int jj = 0; jj < 8; ++jj) acc[i][jj] = gv[jj];
  }
  int t_lo = s0 - 80; if (t_lo < 0) t_lo = 0; t_lo &= ~31;
  int t_hi = s0 + 160; if (t_hi > T) t_hi = T; t_hi = (t_hi + 31) & ~31;
  for (int t0 = t_lo; t0 < t_hi; t0 += TKB) {
    __syncthreads();
    {  // stage P': 32 x 64 (2 float4 per thread)
      int tr = tid >> 4, sc = (tid & 15) * 4;
#pragma unroll
      for (int h = 0; h < 2; ++h) {
        int t = t0 + tr + h * 16;
        float4 p4 = *(const float4*)&pb[(size_t)t * T + s0 + sc];
        float cv = cb[t];
        p4.x -= cv; p4.y -= cv; p4.z -= cv; p4.w -= cv;
        *(float4*)&Pl[tr + h * 16][sc] = p4;
      }
    }
    {  // stage X: 32 x 128 (4 float4 per thread)
      int tr = tid >> 4, c0 = (tid & 15) * 4;
#pragma unroll
      for (int h = 0; h < 2; ++h) {
        const float* xrow = &xb[(size_t)(t0 + tr + h * 16) * D + d0 + c0];
        *(float4*)&Xl[tr + h * 16][c0] = *(const float4*)(xrow);
        *(float4*)&Xl[tr + h * 16][c0 + 64] = *(const float4*)(xrow + 64);
      }
    }
    __syncthreads();
#pragma unroll
    for (int t = 0; t < TKB; ++t) {
      float4 pa = *(const float4*)&Pl[t][ts * 4];
      float4 xa = *(const float4*)&Xl[t][td * 8];
      float4 xc = *(const float4*)&Xl[t][td * 8 + 4];
      float pv[4] = {pa.x, pa.y, pa.z, pa.w};
      float xv[8] = {xa.x, xa.y, xa.z, xa.w, xc.x, xc.y, xc.z, xc.w};
#pragma unroll
      for (int i = 0; i < 4; ++i)
#pragma unroll
        for (int jj = 0; jj < 8; ++jj)
          acc[i][jj] = fmaf(pv[i], xv[jj], acc[i][jj]);
    }
  }
#pragma unroll
  for (int i = 0; i < 4; ++i) {
    int s = s0 + ts * 4 + i;
    float sc = scale[b * T + s];
    float* op = out + ((size_t)b * T + s) * D + d0 + td * 8;
    float4 o0, o1;
    o0.x = acc[i][0] * sc; o0.y = acc[i][1] * sc; o0.z = acc[i][2] * sc; o0.w = acc[i][3] * sc;
    o1.x = acc[i][4] * sc; o1.y = acc[i][5] * sc; o1.z = acc[i][6] * sc; o1.w = acc[i][7] * sc;
    *(float4*)op = o0;
    *(float4*)(op + 4) = o1;
  }
}

extern "C" void kernel_launch(void* const* d_in, const int* in_sizes, int n_in,
                              void* d_out, int out_size, void* d_ws, size_t ws_size,
                              hipStream_t stream) {
  const float* x = (const float*)d_in[0];
  const float* y = (const float*)d_in[1];
  const float* W = (const float*)d_in[2];
  const float* bias = (const float*)d_in[3];
  const float* wscale = (const float*)d_in[4];
  const float* wshift = (const float*)d_in[5];
  float* outp = (float*)d_out;
  float* aligned = outp;                          // [B,T,D] (written last by bmm)
  float* path = outp + (size_t)NB * T * D;        // [B,T,T]
  float* distc = aligned;                         // 21 MB scratch overlaid in aligned region
  float* ws = (float*)d_ws;
  float* xw = ws;
  float* yw = xw + (size_t)NB * T * WD;
  float* scale = yw + (size_t)NB * T * WD;
  float* WeT = scale + (size_t)NB * T;
  float* beff = WeT + (size_t)WD * D;
  float* cvec = beff + WD;
  float* g = cvec + (size_t)NB * T;

  prep_kernel<<<dim3((WD * D) / 256), 256, 0, stream>>>(W, bias, wscale, wshift, WeT, beff);
  proj_kernel<<<dim3((2 * NB * T) / 64), 256, 0, stream>>>(x, y, WeT, beff, xw, yw);
  dist_kernel<<<dim3(20, NB), 256, 0, stream>>>(xw, yw, distc);
  dtw_kernel<<<dim3(NB), 64, 0, stream>>>(distc, path);
  softmax_kernel<<<dim3(NB * T), T, 0, stream>>>(path, cvec);
  gk_kernel<<<dim3(D / 256, NB), 256, 0, stream>>>(x, cvec, g);
  colsum_kernel<<<dim3(T / 64, NB), 256, 0, stream>>>(path, cvec, scale);
  bmm_kernel<<<dim3((D / TDB) * (T / TSB) * NB), 256, 0, stream>>>(path, x, cvec, g, scale, aligned);
}

// Round 19
// 324.524 us; speedup vs baseline: 1.0125x; 1.0125x over previous
//
#include <hip/hip_runtime.h>

#define NB 64
#define T 320
#define D 768
#define WD 32
#define NSTEP 639
#define NBLK 80
#define BSTRIDE (NBLK * 1024)
#define BIG 1e30f
#define LOG2E 1.44269504088896340736f

// DPP lane rotations (VALU, no LDS pipe): ror1 = lane l <- lane (l-1)&63,
// rol1 = lane l <- lane (l+1)&63. gfx9-lineage wave_ror:1/wave_rol:1.
__device__ __forceinline__ float dpp_ror1(float v) {
  return __int_as_float(__builtin_amdgcn_update_dpp(
      0, __float_as_int(v), 0x13C, 0xF, 0xF, true));
}
__device__ __forceinline__ float dpp_rol1(float v) {
  return __int_as_float(__builtin_amdgcn_update_dpp(
      0, __float_as_int(v), 0x134, 0xF, 0xF, true));
}

// ---------------- K_prep: WeT[c][k] = W[k][c]*wscale[k];  beff[k] ----------------
__global__ __launch_bounds__(256) void prep_kernel(
    const float* __restrict__ W, const float* __restrict__ bias,
    const float* __restrict__ wscale, const float* __restrict__ wshift,
    float* __restrict__ WeT, float* __restrict__ beff) {
  int i = blockIdx.x * 256 + threadIdx.x;  // i = c*32 + k
  int c = i >> 5, k = i & 31;
  WeT[i] = W[k * D + c] * wscale[k];
  if (i < WD) beff[i] = bias[i] * wscale[i] + wshift[i];
}

// ---------------- K1: projection v5 (unchanged) ----------------
__global__ __launch_bounds__(256) void proj_kernel(
    const float* __restrict__ x, const float* __restrict__ y,
    const float* __restrict__ WeT, const float* __restrict__ beff,
    float* __restrict__ xw, float* __restrict__ yw) {
  __shared__ float lds[8448];  // = max(64*129, 4*64*33) floats = 33.8 KB
  int tid = threadIdx.x;
  int w = tid >> 6, l = tid & 63;
  int rbase = blockIdx.x * 64;
  float acc[32];
#pragma unroll
  for (int k = 0; k < 32; ++k) acc[k] = 0.f;
#pragma clang loop unroll(disable)
  for (int ch = 0; ch < 6; ++ch) {
    __syncthreads();  // Xl region safe to overwrite
#pragma unroll
    for (int p = 0; p < 8; ++p) {
      int idx = p * 256 + tid;  // 0..2047
      int row = idx >> 5;       // 0..63
      int c4 = idx & 31;        // 0..31
      int r = rbase + row;
      const float* src = (r < NB * T) ? x + (size_t)r * D
                                      : y + (size_t)(r - NB * T) * D;
      float4 v = *(const float4*)(src + ch * 128 + c4 * 4);
      lds[row * 129 + c4 * 4 + 0] = v.x;
      lds[row * 129 + c4 * 4 + 1] = v.y;
      lds[row * 129 + c4 * 4 + 2] = v.z;
      lds[row * 129 + c4 * 4 + 3] = v.w;
    }
    __syncthreads();
    int woff = __builtin_amdgcn_readfirstlane((ch * 128 + w * 32) * 32);
    const float* wp = WeT + woff;
#pragma unroll
    for (int cc = 0; cc < 32; ++cc) {
      float xv = lds[l * 129 + w * 32 + cc];
#pragma unroll
      for (int k = 0; k < 32; ++k)
        acc[k] = fmaf(wp[cc * 32 + k], xv, acc[k]);
    }
  }
  __syncthreads();  // all Xl reads done; reuse lds as part[4][64][33]
#pragma unroll
  for (int k = 0; k < 32; ++k) lds[w * 2112 + l * 33 + k] = acc[k];
  __syncthreads();
  int idx = tid * 8;
  int row = idx >> 5;  // 0..63
  int k0 = idx & 31;   // 0,8,16,24
  float o[8];
#pragma unroll
  for (int e = 0; e < 8; ++e)
    o[e] = lds[0 * 2112 + row * 33 + k0 + e] + lds[1 * 2112 + row * 33 + k0 + e] +
           lds[2 * 2112 + row * 33 + k0 + e] + lds[3 * 2112 + row * 33 + k0 + e] +
           beff[k0 + e];
  int rr = rbase + row;
  float* dst = (rr < NB * T) ? xw + (size_t)rr * WD + k0
                             : yw + (size_t)(rr - NB * T) * WD + k0;
  float4 o0 = {o[0], o[1], o[2], o[3]}, o1 = {o[4], o[5], o[6], o[7]};
  *(float4*)dst = o0;
  *(float4*)(dst + 4) = o1;
}

// ---------------- K0: tiled banded dist, LDS-staged rows (unchanged) ----------------
__global__ __launch_bounds__(256) void dist_kernel(
    const float* __restrict__ xw, const float* __restrict__ yw,
    float* __restrict__ dc) {
  __shared__ float xs[64][33];
  __shared__ float ys[64][33];
  int b = blockIdx.y;
  int cidx = blockIdx.x;            // 0..19
  int t1c = (cidx >> 2) * 64;       // 0,64,...,256
  int t2c = t1c - 88 + (cidx & 3) * 64;  // may be negative / >T
  int tid = threadIdx.x;
  {
    int r = tid >> 2, c4 = tid & 3;
    const float* sx = xw + ((size_t)b * T + t1c + r) * WD;
    *(float4*)&xs[r][c4 * 4] = *(const float4*)(sx + c4 * 4);
    *(float4*)&xs[r][(c4 + 4) * 4] = *(const float4*)(sx + (c4 + 4) * 4);
    int t2r = t2c + r;
    if ((unsigned)t2r < (unsigned)T) {
      const float* sy = yw + ((size_t)b * T + t2r) * WD;
      *(float4*)&ys[r][c4 * 4] = *(const float4*)(sy + c4 * 4);
      *(float4*)&ys[r][(c4 + 4) * 4] = *(const float4*)(sy + (c4 + 4) * 4);
    }
  }
  __syncthreads();
  int ts1 = (tid >> 4) * 4;  // 0..60
  int ts2 = (tid & 15) * 4;  // 0..60
  float acc[4][4];
#pragma unroll
  for (int i = 0; i < 4; ++i)
#pragma unroll
    for (int j = 0; j < 4; ++j) acc[i][j] = 0.f;
#pragma unroll
  for (int c4 = 0; c4 < 8; ++c4) {
    float4 xv[4], yv[4];
#pragma unroll
    for (int i = 0; i < 4; ++i) xv[i] = *(const float4*)&xs[ts1 + i][c4 * 4];
#pragma unroll
    for (int j = 0; j < 4; ++j) yv[j] = *(const float4*)&ys[ts2 + j][c4 * 4];
#pragma unroll
    for (int i = 0; i < 4; ++i)
#pragma unroll
      for (int j = 0; j < 4; ++j) {
        float d0 = xv[i].x - yv[j].x, d1 = xv[i].y - yv[j].y;
        float d2 = xv[i].z - yv[j].z, d3 = xv[i].w - yv[j].w;
        float s = acc[i][j];
        s = fmaf(d0, d0, s); s = fmaf(d1, d1, s);
        s = fmaf(d2, d2, s); s = fmaf(d3, d3, s);
        acc[i][j] = s;
      }
  }
  float* dcb = dc + (size_t)b * BSTRIDE;
#pragma unroll
  for (int i = 0; i < 4; ++i) {
#pragma unroll
    for (int j = 0; j < 4; ++j) {
      int t1 = t1c + ts1 + i;
      int t2 = t2c + ts2 + j;
      int dt = t2 - t1;
      if ((unsigned)t2 < (unsigned)T && dt >= -81 && dt <= 80) {
        int d = t1 + t2;
        int par = (d + 1) & 1;
        int base = (d + 81 - par) >> 1;
        int a = base - t1;
        dcb[((d >> 3) << 10) + (a << 3) + (d & 7)] = acc[i][j] * LOG2E;
      }
    }
  }
}

// ---------------- K2: single-wave banded DP, DPP exchange, base-2 softmin (unchanged) ----------------
#define FSTEP(DP_, DS_, PAR, DVAL)                                             \
  {                                                                            \
    const int d_ = (DVAL);                                                     \
    const int base_ = (d_ + 81 - (PAR)) >> 1;                                  \
    float shP, shS;                                                            \
    if (PAR) { shP = dpp_rol1((l == 0) ? v0b : v0); shS = dpp_rol1(v0b); }     \
    else     { shP = dpp_ror1(v1); shS = dpp_ror1((l == 63) ? v1 : v1b); }     \
    int t1 = base_ - l, t2 = d_ - t1;                                          \
    {                                                                          \
      bool valid = ((unsigned)t1 < (unsigned)T) && ((unsigned)t2 < (unsigned)T); \
      float up, left, diag;                                                    \
      if (PAR) { left = v0; up = shP; diag = v1; }                             \
      else     { up = v1; left = (l == 0) ? 0.f : shP; diag = v0; }            \
      float cu = (t1 > 0) ? up : BIG;                                          \
      float cl = (t2 > 0) ? left : BIG;                                        \
      float cd = (t1 > 0 && t2 > 0) ? diag : BIG;                              \
      float mn = fminf(fminf(cu, cl), cd);                                     \
      float mx = fmaxf(fmaxf(cu, cl), cd);                                     \
      float md = fmaxf(fminf(cu, cl), fminf(fmaxf(cu, cl), cd));               \
      float ss = 1.f + __builtin_amdgcn_exp2f(mn - md) +                       \
                 __builtin_amdgcn_exp2f(mn - mx);                              \
      float val = (DP_) + mn - __builtin_amdgcn_logf(ss);                      \
      if ((DVAL) == 0) val = (DP_);                                            \
      if (valid) {                                                             \
        if (PAR) v1 = val; else v0 = val;                                      \
        outb[t1 * T + t2] = val;                                               \
      }                                                                        \
    }                                                                          \
    {                                                                          \
      int t1b = t1 - 64, t2b = t2 + 64;                                        \
      bool valid = (l < 17) && ((unsigned)t1b < (unsigned)T) &&                \
                   ((unsigned)t2b < (unsigned)T);                              \
      float up, left, diag;                                                    \
      if (PAR) { left = v0b; up = (l == 16) ? 0.f : shS; diag = v1b; }         \
      else     { up = v1b; left = shS; diag = v0b; }                           \
      float cu = (t1b > 0) ? up : BIG;                                         \
      float cl = (t2b > 0) ? left : BIG;                                       \
      float cd = (t1b > 0 && t2b > 0) ? diag : BIG;                            \
      float mn = fminf(fminf(cu, cl), cd);                                     \
      float mx = fmaxf(fmaxf(cu, cl), cd);                                     \
      float md = fmaxf(fminf(cu, cl), fminf(fmaxf(cu, cl), cd));               \
      float ss = 1.f + __builtin_amdgcn_exp2f(mn - md) +                       \
                 __builtin_amdgcn_exp2f(mn - mx);                              \
      float val = (DS_) + mn - __builtin_amdgcn_logf(ss);                      \
      if (valid) {                                                             \
        if (PAR) v1b = val; else v0b = val;                                    \
        outb[t1b * T + t2b] = val;                                             \
      }                                                                        \
    }                                                                          \
  }

#define SSTEP(DP_, DS_, PAR, IOFF)                                             \
  {                                                                            \
    float shP, shS;                                                            \
    if (PAR) { shP = dpp_rol1((l == 0) ? v0b : v0); shS = dpp_rol1(v0b); }     \
    else     { shP = dpp_ror1(v1); shS = dpp_ror1((l == 63) ? v1 : v1b); }     \
    {                                                                          \
      float up, left, diag;                                                    \
      if (PAR) { left = v0; up = shP; diag = v1; }                             \
      else     { up = v1; left = (l == 0) ? 0.f : shP; diag = v0; }            \
      float mn = fminf(fminf(up, left), diag);                                 \
      float mx = fmaxf(fmaxf(up, left), diag);                                 \
      float md = fmaxf(fminf(up, left), fminf(fmaxf(up, left), diag));         \
      float ss = 1.f + __builtin_amdgcn_exp2f(mn - md) +                       \
                 __builtin_amdgcn_exp2f(mn - mx);                              \
      float val = (DP_) + mn - __builtin_amdgcn_logf(ss);                      \
      if (PAR) v1 = val; else v0 = val;                                        \
      outb[io + (IOFF)] = val;                                                 \
    }                                                                          \
    {                                                                          \
      float up, left, diag;                                                    \
      if (PAR) { left = v0b; up = (l == 16) ? 0.f : shS; diag = v1b; }         \
      else     { up = v1b; left = shS; diag = v0b; }                           \
      float mn = fminf(fminf(up, left), diag);                                 \
      float mx = fmaxf(fmaxf(up, left), diag);                                 \
      float md = fmaxf(fminf(up, left), fminf(fmaxf(up, left), diag));         \
      float ss = 1.f + __builtin_amdgcn_exp2f(mn - md) +                       \
                 __builtin_amdgcn_exp2f(mn - mx);                              \
      float val = (DS_) + mn - __builtin_amdgcn_logf(ss);                      \
      if (PAR) v1b = val; else v0b = val;                                      \
      if (l < 17) outb[ioS + (IOFF)] = val;                                    \
    }                                                                          \
  }

#define LOADBLK(R0, R1, S0v, S1v, DBLK)                                        \
  {                                                                            \
    const float4* q_ = (const float4*)(dcb + (DBLK) * 1024 + l * 8);           \
    R0 = q_[0]; R1 = q_[1];                                                    \
    const float4* q2_ = (const float4*)(dcb + (DBLK) * 1024 + (64 + l) * 8);   \
    S0v = q2_[0]; S1v = q2_[1];                                                \
  }

#define BLK8_F(P0, P1, S0v, S1v, DB)                                           \
  FSTEP(P0.x, S0v.x, 1, (DB) + 0) FSTEP(P0.y, S0v.y, 0, (DB) + 1)              \
  FSTEP(P0.z, S0v.z, 1, (DB) + 2) FSTEP(P0.w, S0v.w, 0, (DB) + 3)              \
  FSTEP(P1.x, S1v.x, 1, (DB) + 4) FSTEP(P1.y, S1v.y, 0, (DB) + 5)              \
  FSTEP(P1.z, S1v.z, 1, (DB) + 6) FSTEP(P1.w, S1v.w, 0, (DB) + 7)

#define BLK8_S(P0, P1, S0v, S1v)                                               \
  SSTEP(P0.x, S0v.x, 1, 0)   SSTEP(P0.y, S0v.y, 0, 320)                        \
  SSTEP(P0.z, S0v.z, 1, 321) SSTEP(P0.w, S0v.w, 0, 641)                        \
  io += 642; ioS += 642;                                                       \
  SSTEP(P1.x, S1v.x, 1, 0)   SSTEP(P1.y, S1v.y, 0, 320)                        \
  SSTEP(P1.z, S1v.z, 1, 321) SSTEP(P1.w, S1v.w, 0, 641)                        \
  io += 642; ioS += 642;

__global__ __launch_bounds__(64) void dtw_kernel(
    const float* __restrict__ dc, float* __restrict__ path) {
  int b = blockIdx.x;
  int l = threadIdx.x;
  const float* dcb = dc + (size_t)b * BSTRIDE;
  float* outb = path + (size_t)b * T * T;
  float v0 = 0.f, v1 = 0.f, v0b = 0.f, v1b = 0.f;
  float4 aP0, aP1, aS0, aS1, bP0, bP1, bS0, bS1;
  int io = 0, ioS = 0;

  // d = 0: cell (0,0) = slot 81 = pair a=40 par1. Layout index: a*8+k = 320.
  if (l == 40) {
    float d00 = dcb[320];
    v1 = d00;
    outb[0] = d00;
  }
  LOADBLK(aP0, aP1, aS0, aS1, 0)
#pragma clang loop unroll(disable)
  for (int it = 0; it < 6; ++it) {
    int dbase = it * 16;
    int blk = it * 2;
    LOADBLK(bP0, bP1, bS0, bS1, blk + 1)
    BLK8_F(aP0, aP1, aS0, aS1, dbase)
    LOADBLK(aP0, aP1, aS0, aS1, blk + 2)
    BLK8_F(bP0, bP1, bS0, bS1, dbase + 8)
  }
  io = 28168 - 319 * l;
  ioS = io - 20416;
#pragma clang loop unroll(disable)
  for (int it = 0; it < 27; ++it) {
    int blk = 12 + it * 2;
    LOADBLK(bP0, bP1, bS0, bS1, blk + 1)
    BLK8_S(aP0, aP1, aS0, aS1)
    LOADBLK(aP0, aP1, aS0, aS1, blk + 2)
    BLK8_S(bP0, bP1, bS0, bS1)
  }
#pragma clang loop unroll(disable)
  for (int it = 0; it < 6; ++it) {
    int dbase = 528 + it * 16;
    int blk = 66 + it * 2;
    LOADBLK(bP0, bP1, bS0, bS1, blk + 1)
    BLK8_F(aP0, aP1, aS0, aS1, dbase)
    LOADBLK(aP0, aP1, aS0, aS1, blk + 2)
    BLK8_F(bP0, bP1, bS0, bS1, dbase + 8)
  }
  LOADBLK(bP0, bP1, bS0, bS1, 79)
  BLK8_F(aP0, aP1, aS0, aS1, 624)
  FSTEP(bP0.x, bS0.x, 1, 632) FSTEP(bP0.y, bS0.y, 0, 633)
  FSTEP(bP0.z, bS0.z, 1, 634) FSTEP(bP0.w, bS0.w, 0, 635)
  FSTEP(bP1.x, bS1.x, 1, 636) FSTEP(bP1.y, bS1.y, 0, 637)
  FSTEP(bP1.z, bS1.z, 1, 638)
}

// ---------------- K3: row softmax; path holds base-2 values -> exp2 ----------------
__global__ __launch_bounds__(T) void softmax_kernel(float* __restrict__ path,
                                                    float* __restrict__ cvec) {
  __shared__ float sm1[5], sm2[5];
  int row = blockIdx.x;
  int t1 = row % T;
  int j = threadIdx.x;
  float* p = path + (size_t)row * T;
  bool in = (j >= t1 - 81) && (j <= t1 + 80);
  float v = in ? p[j] : 0.f;  // out-of-band cells are exact 0 in the reference
  float m = v;
#pragma unroll
  for (int off = 32; off >= 1; off >>= 1) m = fminf(m, __shfl_xor(m, off, 64));
  int w = j >> 6;
  if ((j & 63) == 0) sm1[w] = m;
  __syncthreads();
  m = fminf(fminf(fminf(sm1[0], sm1[1]), fminf(sm1[2], sm1[3])), sm1[4]);
  // v, m are DP values scaled by log2e; exp2(m - v) == exp(m_nats - v_nats)
  float e = __builtin_amdgcn_exp2f(m - v);
  float s = e;
#pragma unroll
  for (int off = 32; off >= 1; off >>= 1) s += __shfl_xor(s, off, 64);
  if ((j & 63) == 0) sm2[w] = s;
  __syncthreads();
  s = sm2[0] + sm2[1] + sm2[2] + sm2[3] + sm2[4];
  p[j] = e / s;
  if (j == 0) cvec[row] = __builtin_amdgcn_exp2f(m - 0.f) / s;  // == out-of-band p[j]
}

// ---------------- K3g: g[b][d] = sum_t cvec[b,t] * x[b,t,d] ----------------
__global__ __launch_bounds__(256) void gk_kernel(
    const float* __restrict__ x, const float* __restrict__ cvec,
    float* __restrict__ g) {
  int b = blockIdx.y;
  int d0 = blockIdx.x * 256 + threadIdx.x;
  const float* xb = x + (size_t)b * T * D + d0;
  const float* cb = cvec + b * T;  // wave-uniform reads
  float s = 0.f;
  for (int t = 0; t < T; ++t) s = fmaf(cb[t], xb[(size_t)t * D], s);
  g[b * D + d0] = s;
}

// ---------------- K3b: column scale, band-window + Cb identity (unchanged) ----------------
__global__ __launch_bounds__(256) void colsum_kernel(
    const float* __restrict__ path, const float* __restrict__ cvec,
    float* __restrict__ scale) {
  __shared__ float red[4][64];
  __shared__ float cbred[4];
  int b = blockIdx.y;
  int tid = threadIdx.x;
  int l = tid & 63, tq = tid >> 6;
  int j = blockIdx.x * 64 + l;
  const float* cb = cvec + b * T;
  // Cb
  float c = cb[tid];
  if (tid < 64) c += cb[256 + tid];
#pragma unroll
  for (int off = 32; off >= 1; off >>= 1) c += __shfl_xor(c, off, 64);
  if (l == 0) cbred[tq] = c;
  // band-window quarter sum
  float s = 0.f;
  int t0 = j - 80 + tq * 41;
  const float* p = path + (size_t)b * T * T + j;
#pragma unroll 4
  for (int i = 0; i < 41; ++i) {
    int t = t0 + i;
    if ((unsigned)t < (unsigned)T) s += p[(size_t)t * T] - cb[t];
  }
  red[tq][l] = s;
  __syncthreads();
  if (tq == 0) {
    float cs = red[0][l] + red[1][l] + red[2][l] + red[3][l] +
               (cbred[0] + cbred[1] + cbred[2] + cbred[3]);
    scale[b * T + j] = 1.f / (cs + 1e-10f);
  }
}

// ---------------- K4: banded bmm, TKB=16, 128-wide d-tiles + XCD grouping ----------------
#define TSB 64
#define TDB 128
#define TKB 16
__global__ __launch_bounds__(256) void bmm_kernel(
    const float* __restrict__ path, const float* __restrict__ x,
    const float* __restrict__ cvec, const float* __restrict__ g,
    const float* __restrict__ scale, float* __restrict__ out) {
  __shared__ __align__(16) float Pl[TKB][TSB];
  __shared__ __align__(16) float Xl[TKB][TDB];
  int bid = blockIdx.x;
  int wgid = (bid & 7) * 240 + (bid >> 3);
  int b = wgid / 30;
  int r = wgid - b * 30;
  int s0 = (r / 6) * TSB;
  int d0 = (r % 6) * TDB;
  int tid = threadIdx.x;
  int ts = tid & 15, td = tid >> 4;  // 16 s-groups (4 rows) x 16 d-groups (8 cols)
  const float* pb = path + (size_t)b * T * T;
  const float* xb = x + (size_t)b * T * D;
  const float* cb = cvec + b * T;
  float acc[4][8];
  {
    const float* gb = g + b * D + d0 + td * 8;
    float4 g0 = *(const float4*)gb;
    float4 g1 = *(const float4*)(gb + 4);
    float gv[8] = {g0.x, g0.y, g0.z, g0.w, g1.x, g1.y, g1.z, g1.w};
#pragma unroll
    for (int i = 0; i < 4; ++i)
#pragma unroll
      for (int jj = 0; jj < 8; ++jj) acc[i][jj] = gv[jj];
  }
  int t_lo = s0 - 80; if (t_lo < 0) t_lo = 0; t_lo &= ~15;
  int t_hi = (s0 + 160) & ~15; if (t_hi > T) t_hi = T;
  for (int t0 = t_lo; t0 < t_hi; t0 += TKB) {
    __syncthreads();
    {  // stage P': 16 x 64
      int tr = tid >> 4, sc = (tid & 15) * 4;
      float4 p4 = *(const float4*)&pb[(size_t)(t0 + tr) * T + s0 + sc];
      float cv = cb[t0 + tr];
      p4.x -= cv; p4.y -= cv; p4.z -= cv; p4.w -= cv;
      *(float4*)&Pl[tr][sc] = p4;
    }
    {  // stage X: 16 x 128
      int tr = tid >> 4, c0 = (tid & 15) * 4;
      const float* xrow = &xb[(size_t)(t0 + tr) * D + d0 + c0];
      *(float4*)&Xl[tr][c0] = *(const float4*)(xrow);
      *(float4*)&Xl[tr][c0 + 64] = *(const float4*)(xrow + 64);
    }
    __syncthreads();
#pragma unroll
    for (int t = 0; t < TKB; ++t) {
      float4 pa = *(const float4*)&Pl[t][ts * 4];
      float4 xa = *(const float4*)&Xl[t][td * 8];
      float4 xc = *(const float4*)&Xl[t][td * 8 + 4];
      float pv[4] = {pa.x, pa.y, pa.z, pa.w};
      float xv[8] = {xa.x, xa.y, xa.z, xa.w, xc.x, xc.y, xc.z, xc.w};
#pragma unroll
      for (int i = 0; i < 4; ++i)
#pragma unroll
        for (int jj = 0; jj < 8; ++jj)
          acc[i][jj] = fmaf(pv[i], xv[jj], acc[i][jj]);
    }
  }
#pragma unroll
  for (int i = 0; i < 4; ++i) {
    int s = s0 + ts * 4 + i;
    float sc = scale[b * T + s];
    float* op = out + ((size_t)b * T + s) * D + d0 + td * 8;
    float4 o0, o1;
    o0.x = acc[i][0] * sc; o0.y = acc[i][1] * sc; o0.z = acc[i][2] * sc; o0.w = acc[i][3] * sc;
    o1.x = acc[i][4] * sc; o1.y = acc[i][5] * sc; o1.z = acc[i][6] * sc; o1.w = acc[i][7] * sc;
    *(float4*)op = o0;
    *(float4*)(op + 4) = o1;
  }
}

extern "C" void kernel_launch(void* const* d_in, const int* in_sizes, int n_in,
                              void* d_out, int out_size, void* d_ws, size_t ws_size,
                              hipStream_t stream) {
  const float* x = (const float*)d_in[0];
  const float* y = (const float*)d_in[1];
  const float* W = (const float*)d_in[2];
  const float* bias = (const float*)d_in[3];
  const float* wscale = (const float*)d_in[4];
  const float* wshift = (const float*)d_in[5];
  float* outp = (float*)d_out;
  float* aligned = outp;                          // [B,T,D] (written last by bmm)
  float* path = outp + (size_t)NB * T * D;        // [B,T,T]
  float* distc = aligned;                         // 21 MB scratch overlaid in aligned region
  float* ws = (float*)d_ws;
  float* xw = ws;
  float* yw = xw + (size_t)NB * T * WD;
  float* scale = yw + (size_t)NB * T * WD;
  float* WeT = scale + (size_t)NB * T;
  float* beff = WeT + (size_t)WD * D;
  float* cvec = beff + WD;
  float* g = cvec + (size_t)NB * T;

  prep_kernel<<<dim3((WD * D) / 256), 256, 0, stream>>>(W, bias, wscale, wshift, WeT, beff);
  proj_kernel<<<dim3((2 * NB * T) / 64), 256, 0, stream>>>(x, y, WeT, beff, xw, yw);
  dist_kernel<<<dim3(20, NB), 256, 0, stream>>>(xw, yw, distc);
  dtw_kernel<<<dim3(NB), 64, 0, stream>>>(distc, path);
  softmax_kernel<<<dim3(NB * T), T, 0, stream>>>(path, cvec);
  gk_kernel<<<dim3(D / 256, NB), 256, 0, stream>>>(x, cvec, g);
  colsum_kernel<<<dim3(T / 64, NB), 256, 0, stream>>>(path, cvec, scale);
  bmm_kernel<<<dim3((D / TDB) * (T / TSB) * NB), 256, 0, stream>>>(path, x, cvec, g, scale, aligned);
}